// Round 14
// baseline (89.814 us; speedup 1.0000x reference)
//
#include <hip/hip_runtime.h>
#include <hip/hip_fp8.h>
#include <math.h>

// Problem geometry
#define DD 128
#define HH 128
#define WW 128
constexpr int   DHW   = DD * HH * WW;        // 2^21
constexpr int   BATCH = 2;
constexpr long long NTOT = (long long)BATCH * 3 * DHW;

// ws layout: [0, 16KB) block partials only (pack pre-pass fused away)
constexpr size_t WS_NEEDED = 4096 * sizeof(float);

#if defined(__has_builtin)
#if __has_builtin(__builtin_amdgcn_cvt_f32_fp8) && __has_builtin(__builtin_amdgcn_cvt_pk_fp8_f32)
#define USE_FP8_BUILTIN 1
#endif
#if __has_builtin(__builtin_amdgcn_cvt_pk_f32_fp8)
#define USE_FP8_PK 1
#endif
#endif

typedef float f32x2 __attribute__((ext_vector_type(2)));

__device__ __forceinline__ unsigned enc3(float a, float b, float c) {
#ifdef USE_FP8_BUILTIN
    int lo = __builtin_amdgcn_cvt_pk_fp8_f32(a, b, 0, false);
    int hi = __builtin_amdgcn_cvt_pk_fp8_f32(c, 0.f, 0, false);
    return (unsigned)(lo & 0xffff) | ((unsigned)hi << 16);
#else
    __hip_fp8_e4m3 fa(a), fb(b), fc(c);
    return (unsigned)fa.__x | ((unsigned)fb.__x << 8) | ((unsigned)fc.__x << 16);
#endif
}

__device__ __forceinline__ f32x2 dec_zy(unsigned w) {
#ifdef USE_FP8_PK
    return __builtin_amdgcn_cvt_pk_f32_fp8((int)w, false);
#else
    __hip_fp8_e4m3 ha, hb;
    ha.__x = (__hip_fp8_storage_t)(w & 0xff);
    hb.__x = (__hip_fp8_storage_t)((w >> 8) & 0xff);
    f32x2 r; r.x = (float)ha; r.y = (float)hb;
    return r;
#endif
}

__device__ __forceinline__ float dec_x(unsigned w) {
#ifdef USE_FP8_BUILTIN
    return __builtin_amdgcn_cvt_f32_fp8((int)w, 2);
#else
    __hip_fp8_e4m3 h;
    h.__x = (__hip_fp8_storage_t)((w >> 16) & 0xff);
    return (float)h;
#endif
}

// ---------------------------------------------------------------------------
// Fused main: stage bwd fp32 -> fp8x4 LDS region on the fly, then
// LDS trilinear gather. Tile 8(z) x 8(y) x 16(x); region 14 x 14 x 25
// (halo z/y=3, x=4) = 19.6 KB -> 8 blocks/CU. fwd prefetched before staging.
// Staging clamped; compute uses validity-masked weights with unclamped
// region indices (exact). Out-of-region corners read fp32 bwd directly.
// ---------------------------------------------------------------------------
constexpr int TZ = 8, TY = 8, TX = 16;
constexpr int RZ = 14, RY = 14, RX = 25;
constexpr int RN = RZ * RY * RX;             // 4900 dwords = 19600 B
constexpr int GRID_MAIN = BATCH * (DD / TZ) * (HH / TY) * (WW / TX);  // 4096

__global__ __launch_bounds__(256)
void icl_fused_kernel(const float* __restrict__ fwd,
                      const float* __restrict__ bwd,
                      float* __restrict__ partial) {
    __shared__ unsigned rgn[RN];
    __shared__ float smem[4];

    // XCD-aware swizzle (4096 % 8 == 0 -> bijective)
    const int swz = (blockIdx.x & 7) * (GRID_MAIN / 8) + (blockIdx.x >> 3);
    const int b   = swz >> 11;               // 2048 tiles per batch
    const int rem = swz & 2047;              // 16(z) x 16(y) x 8(x)
    const int tz0 = (rem >> 7) << 3;
    const int ty0 = ((rem >> 3) & 15) << 3;
    const int tx0 = (rem & 7) << 4;
    const int oz = tz0 - 3, oy = ty0 - 3, ox = tx0 - 4;

    const float* gb = bwd + (size_t)b * 3 * DHW;
    const int t = threadIdx.x;

    // ---- compute-phase indices + EARLY fwd loads (prefetch) ------------
    const int zl = t >> 5;                    // 0..7
    const int yl = (t >> 2) & 7;              // 0..7
    const int xo = (t & 3) << 2;              // 0,4,8,12
    const int z = tz0 + zl, y = ty0 + yl, x4 = tx0 + xo;
    const int v = (z << 14) + (y << 7) + x4;

    const float* f = fwd + (size_t)b * 3 * DHW;
    const float4 qz = *(const float4*)(f + v);
    const float4 qy = *(const float4*)(f + v + DHW);
    const float4 qx = *(const float4*)(f + v + 2 * DHW);

    // ---- stage + encode: one (rz,ry) row of RX=25 voxels per thread ----
    if (t < RZ * RY) {
        const int rz = t / RY, ry = t % RY;
        const int gz = min(max(oz + rz, 0), DD - 1);
        const int gy = min(max(oy + ry, 0), HH - 1);
        const float* r0 = gb + (((gz << 7) + gy) << 7);
        unsigned* dst = rgn + t * RX;
        if (ox >= 0 && ox + RX <= WW) {      // block-uniform branch
            const float4* p0 = (const float4*)(r0 + ox);
            const float4* p1 = (const float4*)(r0 + ox + DHW);
            const float4* p2 = (const float4*)(r0 + ox + 2 * DHW);
#pragma unroll
            for (int c = 0; c < 6; ++c) {
                const float4 a0 = p0[c], a1 = p1[c], a2 = p2[c];
                dst[4 * c + 0] = enc3(a0.x, a1.x, a2.x);
                dst[4 * c + 1] = enc3(a0.y, a1.y, a2.y);
                dst[4 * c + 2] = enc3(a0.z, a1.z, a2.z);
                dst[4 * c + 3] = enc3(a0.w, a1.w, a2.w);
            }
            dst[24] = enc3(r0[ox + 24], r0[ox + 24 + DHW],
                           r0[ox + 24 + 2 * DHW]);
        } else {
#pragma unroll
            for (int c = 0; c < RX; ++c) {
                const int gx = min(max(ox + c, 0), WW - 1);
                dst[c] = enc3(r0[gx], r0[gx + DHW], r0[gx + 2 * DHW]);
            }
        }
    }
    __syncthreads();

    // ---- compute: 4 x-consecutive voxels per thread --------------------
    const float fzv[4] = {qz.x, qz.y, qz.z, qz.w};
    const float fyv[4] = {qy.x, qy.y, qy.z, qy.w};
    const float fxv[4] = {qx.x, qx.y, qx.z, qx.w};
    const float zf = (float)z, yf = (float)y;

    float acc = 0.f;
#pragma unroll
    for (int j = 0; j < 4; ++j) {
        const float fz = fzv[j], fy = fyv[j], fx = fxv[j];
        const float cz = zf + fz;
        const float cy = yf + fy;
        const float cx = (float)(x4 + j) + fx;

        const float z0f = floorf(cz), y0f = floorf(cy), x0f = floorf(cx);
        const float wz = cz - z0f, wy = cy - y0f, wx = cx - x0f;
        const int z0 = (int)z0f, y0 = (int)y0f, x0 = (int)x0f;

        // validity-masked axis weights (reference semantics)
        const float az0 = ((unsigned)z0 < (unsigned)DD) ? (1.f - wz) : 0.f;
        const float az1 = ((unsigned)(z0 + 1) < (unsigned)DD) ? wz : 0.f;
        const float ay0 = ((unsigned)y0 < (unsigned)HH) ? (1.f - wy) : 0.f;
        const float ay1 = ((unsigned)(y0 + 1) < (unsigned)HH) ? wy : 0.f;
        const float ax0 = ((unsigned)x0 < (unsigned)WW) ? (1.f - wx) : 0.f;
        const float ax1 = ((unsigned)(x0 + 1) < (unsigned)WW) ? wx : 0.f;

        const float p00 = az0 * ay0, p01 = az0 * ay1;
        const float p10 = az1 * ay0, p11 = az1 * ay1;

        const int rz = z0 - oz, ry = y0 - oy, rx = x0 - ox;
        const bool inr = ((unsigned)rz <= (unsigned)(RZ - 2)) &
                         ((unsigned)ry <= (unsigned)(RY - 2)) &
                         ((unsigned)rx <= (unsigned)(RX - 2));

        f32x2 ozy = {0.f, 0.f};
        float oxs = 0.f;
        if (__builtin_expect(inr, 1)) {
            const int base = rz * (RY * RX) + ry * RX + rx;
            const unsigned w000 = rgn[base];
            const unsigned w001 = rgn[base + 1];
            const unsigned w010 = rgn[base + RX];
            const unsigned w011 = rgn[base + RX + 1];
            const unsigned w100 = rgn[base + RY * RX];
            const unsigned w101 = rgn[base + RY * RX + 1];
            const unsigned w110 = rgn[base + RY * RX + RX];
            const unsigned w111 = rgn[base + RY * RX + RX + 1];

            const float a000 = p00 * ax0, a001 = p00 * ax1;
            const float a010 = p01 * ax0, a011 = p01 * ax1;
            const float a100 = p10 * ax0, a101 = p10 * ax1;
            const float a110 = p11 * ax0, a111 = p11 * ax1;

            const f32x2 s000 = {a000, a000}, s001 = {a001, a001};
            const f32x2 s010 = {a010, a010}, s011 = {a011, a011};
            const f32x2 s100 = {a100, a100}, s101 = {a101, a101};
            const f32x2 s110 = {a110, a110}, s111 = {a111, a111};
            ozy += dec_zy(w000) * s000 + dec_zy(w001) * s001
                 + dec_zy(w010) * s010 + dec_zy(w011) * s011
                 + dec_zy(w100) * s100 + dec_zy(w101) * s101
                 + dec_zy(w110) * s110 + dec_zy(w111) * s111;
            oxs += a000 * dec_x(w000) + a001 * dec_x(w001)
                 + a010 * dec_x(w010) + a011 * dec_x(w011)
                 + a100 * dec_x(w100) + a101 * dec_x(w101)
                 + a110 * dec_x(w110) + a111 * dec_x(w111);
        } else {
            // rare global fallback: fp32 bwd directly (exact)
#pragma unroll
            for (int c = 0; c < 8; ++c) {
                const int dz = c >> 2, dy = (c >> 1) & 1, dx = c & 1;
                const int zc = min(max(z0 + dz, 0), DD - 1);
                const int yc = min(max(y0 + dy, 0), HH - 1);
                const int xc = min(max(x0 + dx, 0), WW - 1);
                const float a = (dz ? az1 : az0) * (dy ? ay1 : ay0) *
                                (dx ? ax1 : ax0);
                const int gi = (((zc << 7) + yc) << 7) + xc;
                ozy.x += a * gb[gi];
                ozy.y += a * gb[gi + DHW];
                oxs   += a * gb[gi + 2 * DHW];
            }
        }
        const float c0 = fz + ozy.x;
        const float c1 = fy + ozy.y;
        const float c2 = fx + oxs;
        acc += c0 * c0 + c1 * c1 + c2 * c2;
    }

    // wave-64 shuffle reduction
#pragma unroll
    for (int off = 32; off > 0; off >>= 1)
        acc += __shfl_down(acc, off, 64);

    if ((t & 63) == 0) smem[t >> 6] = acc;
    __syncthreads();
    if (t == 0)
        partial[swz] = smem[0] + smem[1] + smem[2] + smem[3];
}

// ---------------------------------------------------------------------------
// Fallback (fp32 exact, round-1 style): used only if ws too small.
// ---------------------------------------------------------------------------
__global__ __launch_bounds__(256)
void icl_partial_kernel(const float* __restrict__ fwd,
                        const float* __restrict__ bwd,
                        float* __restrict__ partial) {
    const int tid = blockIdx.x * blockDim.x + threadIdx.x;
    const int b = tid >> 21;
    const int v = tid & (DHW - 1);
    const int z = v >> 14;
    const int y = (v >> 7) & 127;
    const int x = v & 127;

    const float* f = fwd + (size_t)b * 3 * DHW;
    const float fz = f[v];
    const float fy = f[v + DHW];
    const float fx = f[v + 2 * DHW];

    const float cz = (float)z + fz, cy = (float)y + fy, cx = (float)x + fx;
    const float z0f = floorf(cz), y0f = floorf(cy), x0f = floorf(cx);
    const float wz = cz - z0f, wy = cy - y0f, wx = cx - x0f;
    const int z0 = (int)z0f, y0 = (int)y0f, x0 = (int)x0f;

    const float* g = bwd + (size_t)b * 3 * DHW;
    float o0 = 0.f, o1 = 0.f, o2 = 0.f;
#pragma unroll
    for (int dz = 0; dz < 2; ++dz) {
        const int zi = z0 + dz;
        const bool vz = (zi >= 0) & (zi < DD);
        const int zc = min(max(zi, 0), DD - 1);
        const float az = dz ? wz : 1.f - wz;
#pragma unroll
        for (int dy = 0; dy < 2; ++dy) {
            const int yi = y0 + dy;
            const bool vy = (yi >= 0) & (yi < HH);
            const int yc = min(max(yi, 0), HH - 1);
            const float ay = dy ? wy : 1.f - wy;
#pragma unroll
            for (int dx = 0; dx < 2; ++dx) {
                const int xi = x0 + dx;
                const bool vx = (xi >= 0) & (xi < WW);
                const int xc = min(max(xi, 0), WW - 1);
                const float ax = dx ? wx : 1.f - wx;
                const float w = (vz & vy & vx) ? (az * ay * ax) : 0.f;
                const int idx = (zc * HH + yc) * WW + xc;
                o0 += w * g[idx];
                o1 += w * g[idx + DHW];
                o2 += w * g[idx + 2 * DHW];
            }
        }
    }
    const float c0 = fz + o0, c1 = fy + o1, c2 = fx + o2;
    float acc = c0 * c0 + c1 * c1 + c2 * c2;
#pragma unroll
    for (int off = 32; off > 0; off >>= 1)
        acc += __shfl_down(acc, off, 64);
    __shared__ float smem[4];
    if ((threadIdx.x & 63) == 0) smem[threadIdx.x >> 6] = acc;
    __syncthreads();
    if (threadIdx.x == 0)
        partial[blockIdx.x] = smem[0] + smem[1] + smem[2] + smem[3];
}

// ---------------------------------------------------------------------------
// Final deterministic reduction (double), divide by N, nan_to_num.
// ---------------------------------------------------------------------------
__global__ __launch_bounds__(256)
void icl_final_kernel(const float* __restrict__ partial, int n,
                      float* __restrict__ out) {
    double acc = 0.0;
    for (int i = threadIdx.x; i < n; i += 256)
        acc += (double)partial[i];
#pragma unroll
    for (int off = 32; off > 0; off >>= 1)
        acc += __shfl_down(acc, off, 64);
    __shared__ double smem[4];
    if ((threadIdx.x & 63) == 0) smem[threadIdx.x >> 6] = acc;
    __syncthreads();
    if (threadIdx.x == 0) {
        const double total = smem[0] + smem[1] + smem[2] + smem[3];
        float r = (float)(total / (double)NTOT);
        if (isnan(r)) r = 0.f;
        else if (isinf(r)) r = (r > 0.f) ? 1000.f : 0.f;
        out[0] = r;
    }
}

// ---------------------------------------------------------------------------
extern "C" void kernel_launch(void* const* d_in, const int* in_sizes, int n_in,
                              void* d_out, int out_size, void* d_ws, size_t ws_size,
                              hipStream_t stream) {
    const float* fwd = (const float*)d_in[0];
    const float* bwd = (const float*)d_in[1];
    float* out = (float*)d_out;
    float* partial = (float*)d_ws;

    if (ws_size >= WS_NEEDED) {
        icl_fused_kernel<<<GRID_MAIN, 256, 0, stream>>>(fwd, bwd, partial);
        icl_final_kernel<<<1, 256, 0, stream>>>(partial, GRID_MAIN, out);
    } else {
        const int grid = (BATCH * DHW) / 256;            // 16384
        icl_partial_kernel<<<grid, 256, 0, stream>>>(fwd, bwd, partial);
        icl_final_kernel<<<1, 256, 0, stream>>>(partial, grid, out);
    }
}

// Round 15
// 45.120 us; speedup vs baseline: 1.9906x; 1.9906x over previous
//
#include <hip/hip_runtime.h>
#include <hip/hip_fp8.h>
#include <math.h>

// Problem geometry
#define DD 128
#define HH 128
#define WW 128
constexpr int   DHW   = DD * HH * WW;        // 2^21
constexpr int   BATCH = 2;
constexpr long long NTOT = (long long)BATCH * 3 * DHW;

// ws layout: [0, 64KB) block partials, [64KB, +B*DHW*4) fp8x4 packed bwd
// pk4[b][z][y][x] : 4B word, bytes (ch0=z, ch1=y, ch2=x, pad)
constexpr size_t WS_PARTIAL_BYTES = 65536;
constexpr size_t WS_NEEDED = WS_PARTIAL_BYTES + (size_t)BATCH * DHW * 4;

#if defined(__has_builtin)
#if __has_builtin(__builtin_amdgcn_cvt_f32_fp8) && __has_builtin(__builtin_amdgcn_cvt_pk_fp8_f32)
#define USE_FP8_BUILTIN 1
#endif
#if __has_builtin(__builtin_amdgcn_cvt_pk_f32_fp8)
#define USE_FP8_PK 1
#endif
#endif

typedef float f32x2 __attribute__((ext_vector_type(2)));

__device__ __forceinline__ unsigned enc3(float a, float b, float c) {
#ifdef USE_FP8_BUILTIN
    int lo = __builtin_amdgcn_cvt_pk_fp8_f32(a, b, 0, false);
    int hi = __builtin_amdgcn_cvt_pk_fp8_f32(c, 0.f, 0, false);
    return (unsigned)(lo & 0xffff) | ((unsigned)hi << 16);
#else
    __hip_fp8_e4m3 fa(a), fb(b), fc(c);
    return (unsigned)fa.__x | ((unsigned)fb.__x << 8) | ((unsigned)fc.__x << 16);
#endif
}

__device__ __forceinline__ f32x2 dec_zy(unsigned w) {
#ifdef USE_FP8_PK
    return __builtin_amdgcn_cvt_pk_f32_fp8((int)w, false);
#else
    __hip_fp8_e4m3 ha, hb;
    ha.__x = (__hip_fp8_storage_t)(w & 0xff);
    hb.__x = (__hip_fp8_storage_t)((w >> 8) & 0xff);
    f32x2 r; r.x = (float)ha; r.y = (float)hb;
    return r;
#endif
}

__device__ __forceinline__ float dec_x(unsigned w) {
#ifdef USE_FP8_BUILTIN
    return __builtin_amdgcn_cvt_f32_fp8((int)w, 2);
#else
    __hip_fp8_e4m3 h;
    h.__x = (__hip_fp8_storage_t)((w >> 16) & 0xff);
    return (float)h;
#endif
}

// ---------------------------------------------------------------------------
// Pack: bwd [B,3,DHW] f32 planes -> plain fp8x4 volume (4B/voxel).
// Full coverage: 2^20 threads x 4 voxels = B*DHW.
// ---------------------------------------------------------------------------
__global__ __launch_bounds__(256)
void icl_pack4_kernel(const float* __restrict__ bwd,
                      unsigned* __restrict__ pk4) {
    const int t = blockIdx.x * 256 + threadIdx.x;    // [0, 2^20)
    const int b = t >> 19;
    const int v = (t & ((1 << 19) - 1)) << 2;
    const float* g = bwd + (size_t)b * 3 * DHW;
    const float4 a0 = *(const float4*)(g + v);
    const float4 a1 = *(const float4*)(g + v + DHW);
    const float4 a2 = *(const float4*)(g + v + 2 * DHW);
    uint4 o;
    o.x = enc3(a0.x, a1.x, a2.x);
    o.y = enc3(a0.y, a1.y, a2.y);
    o.z = enc3(a0.z, a1.z, a2.z);
    o.w = enc3(a0.w, a1.w, a2.w);
    *(uint4*)(pk4 + (size_t)b * DHW + v) = o;
}

// ---------------------------------------------------------------------------
// Main: LDS-staged trilinear gather, TLP-tuned (round-13 best config).
// Tile 8(z) x 8(y) x 16(x); region 14 x 14 x 25 (halo z/y=3, x=4) = 19.6 KB
// -> 8 blocks/CU. fwd loads issued BEFORE staging (HBM latency hides under
// stage + barrier). Staging clamped; compute uses validity-masked weights
// with unclamped region indices (exact). Out-of-region corners take the
// exec-masked exact global fallback.
// ---------------------------------------------------------------------------
constexpr int TZ = 8, TY = 8, TX = 16;
constexpr int RZ = 14, RY = 14, RX = 25;
constexpr int RN = RZ * RY * RX;             // 4900 dwords = 19600 B
constexpr int GRID_MAIN = BATCH * (DD / TZ) * (HH / TY) * (WW / TX);  // 4096

__global__ __launch_bounds__(256)
void icl_lds_kernel(const float* __restrict__ fwd,
                    const unsigned* __restrict__ pk4,
                    float* __restrict__ partial) {
    __shared__ unsigned rgn[RN];
    __shared__ float smem[4];

    // XCD-aware swizzle (4096 % 8 == 0 -> bijective)
    const int swz = (blockIdx.x & 7) * (GRID_MAIN / 8) + (blockIdx.x >> 3);
    const int b   = swz >> 11;               // 2048 tiles per batch
    const int rem = swz & 2047;              // 16(z) x 16(y) x 8(x)
    const int tz0 = (rem >> 7) << 3;
    const int ty0 = ((rem >> 3) & 15) << 3;
    const int tx0 = (rem & 7) << 4;
    const int oz = tz0 - 3, oy = ty0 - 3, ox = tx0 - 4;

    const unsigned* gpk = pk4 + ((size_t)b << 21);
    const int t = threadIdx.x;

    // ---- compute-phase indices + EARLY fwd loads (prefetch) ------------
    const int zl = t >> 5;                    // 0..7
    const int yl = (t >> 2) & 7;              // 0..7
    const int xo = (t & 3) << 2;              // 0,4,8,12
    const int z = tz0 + zl, y = ty0 + yl, x4 = tx0 + xo;
    const int v = (z << 14) + (y << 7) + x4;

    const float* f = fwd + (size_t)b * 3 * DHW;
    const float4 qz = *(const float4*)(f + v);
    const float4 qy = *(const float4*)(f + v + DHW);
    const float4 qx = *(const float4*)(f + v + 2 * DHW);

    // ---- stage: rows 0..RZ*RY-1, one row of RX=25 dwords each ----------
    if (t < RZ * RY) {
        const int rz = t / RY, ry = t % RY;
        const int gz = min(max(oz + rz, 0), DD - 1);
        const int gy = min(max(oy + ry, 0), HH - 1);
        const unsigned* rowp = gpk + (((gz << 7) + gy) << 7);
        unsigned* dst = rgn + t * RX;
        if (ox >= 0 && ox + RX <= WW) {      // block-uniform branch
            const uint4* s4 = (const uint4*)(rowp + ox);
#pragma unroll
            for (int c = 0; c < 6; ++c) {
                const uint4 q = s4[c];
                dst[4 * c + 0] = q.x; dst[4 * c + 1] = q.y;
                dst[4 * c + 2] = q.z; dst[4 * c + 3] = q.w;
            }
            dst[24] = rowp[ox + 24];
        } else {
#pragma unroll
            for (int c = 0; c < RX; ++c)
                dst[c] = rowp[min(max(ox + c, 0), WW - 1)];
        }
    }
    __syncthreads();

    // ---- compute: 4 x-consecutive voxels per thread --------------------
    const float fzv[4] = {qz.x, qz.y, qz.z, qz.w};
    const float fyv[4] = {qy.x, qy.y, qy.z, qy.w};
    const float fxv[4] = {qx.x, qx.y, qx.z, qx.w};
    const float zf = (float)z, yf = (float)y;

    float acc = 0.f;
#pragma unroll
    for (int j = 0; j < 4; ++j) {
        const float fz = fzv[j], fy = fyv[j], fx = fxv[j];
        const float cz = zf + fz;
        const float cy = yf + fy;
        const float cx = (float)(x4 + j) + fx;

        const float z0f = floorf(cz), y0f = floorf(cy), x0f = floorf(cx);
        const float wz = cz - z0f, wy = cy - y0f, wx = cx - x0f;
        const int z0 = (int)z0f, y0 = (int)y0f, x0 = (int)x0f;

        // validity-masked axis weights (reference semantics)
        const float az0 = ((unsigned)z0 < (unsigned)DD) ? (1.f - wz) : 0.f;
        const float az1 = ((unsigned)(z0 + 1) < (unsigned)DD) ? wz : 0.f;
        const float ay0 = ((unsigned)y0 < (unsigned)HH) ? (1.f - wy) : 0.f;
        const float ay1 = ((unsigned)(y0 + 1) < (unsigned)HH) ? wy : 0.f;
        const float ax0 = ((unsigned)x0 < (unsigned)WW) ? (1.f - wx) : 0.f;
        const float ax1 = ((unsigned)(x0 + 1) < (unsigned)WW) ? wx : 0.f;

        const float p00 = az0 * ay0, p01 = az0 * ay1;
        const float p10 = az1 * ay0, p11 = az1 * ay1;

        const int rz = z0 - oz, ry = y0 - oy, rx = x0 - ox;
        const bool inr = ((unsigned)rz <= (unsigned)(RZ - 2)) &
                         ((unsigned)ry <= (unsigned)(RY - 2)) &
                         ((unsigned)rx <= (unsigned)(RX - 2));

        f32x2 ozy = {0.f, 0.f};
        float oxs = 0.f;
        if (__builtin_expect(inr, 1)) {
            const int base = rz * (RY * RX) + ry * RX + rx;
            const unsigned w000 = rgn[base];
            const unsigned w001 = rgn[base + 1];
            const unsigned w010 = rgn[base + RX];
            const unsigned w011 = rgn[base + RX + 1];
            const unsigned w100 = rgn[base + RY * RX];
            const unsigned w101 = rgn[base + RY * RX + 1];
            const unsigned w110 = rgn[base + RY * RX + RX];
            const unsigned w111 = rgn[base + RY * RX + RX + 1];

            const float a000 = p00 * ax0, a001 = p00 * ax1;
            const float a010 = p01 * ax0, a011 = p01 * ax1;
            const float a100 = p10 * ax0, a101 = p10 * ax1;
            const float a110 = p11 * ax0, a111 = p11 * ax1;

            const f32x2 s000 = {a000, a000}, s001 = {a001, a001};
            const f32x2 s010 = {a010, a010}, s011 = {a011, a011};
            const f32x2 s100 = {a100, a100}, s101 = {a101, a101};
            const f32x2 s110 = {a110, a110}, s111 = {a111, a111};
            ozy += dec_zy(w000) * s000 + dec_zy(w001) * s001
                 + dec_zy(w010) * s010 + dec_zy(w011) * s011
                 + dec_zy(w100) * s100 + dec_zy(w101) * s101
                 + dec_zy(w110) * s110 + dec_zy(w111) * s111;
            oxs += a000 * dec_x(w000) + a001 * dec_x(w001)
                 + a010 * dec_x(w010) + a011 * dec_x(w011)
                 + a100 * dec_x(w100) + a101 * dec_x(w101)
                 + a110 * dec_x(w110) + a111 * dec_x(w111);
        } else {
            // rare global fallback (exact same weight masks, clamped idx)
#pragma unroll
            for (int c = 0; c < 8; ++c) {
                const int dz = c >> 2, dy = (c >> 1) & 1, dx = c & 1;
                const int zc = min(max(z0 + dz, 0), DD - 1);
                const int yc = min(max(y0 + dy, 0), HH - 1);
                const int xc = min(max(x0 + dx, 0), WW - 1);
                const float a = (dz ? az1 : az0) * (dy ? ay1 : ay0) *
                                (dx ? ax1 : ax0);
                const unsigned w = gpk[(((zc << 7) + yc) << 7) + xc];
                const f32x2 s = {a, a};
                ozy += dec_zy(w) * s;
                oxs += a * dec_x(w);
            }
        }
        const float c0 = fz + ozy.x;
        const float c1 = fy + ozy.y;
        const float c2 = fx + oxs;
        acc += c0 * c0 + c1 * c1 + c2 * c2;
    }

    // wave-64 shuffle reduction
#pragma unroll
    for (int off = 32; off > 0; off >>= 1)
        acc += __shfl_down(acc, off, 64);

    if ((t & 63) == 0) smem[t >> 6] = acc;
    __syncthreads();
    if (t == 0)
        partial[swz] = smem[0] + smem[1] + smem[2] + smem[3];
}

// ---------------------------------------------------------------------------
// Fallback (fp32 exact, round-1 style): used only if ws too small.
// ---------------------------------------------------------------------------
__global__ __launch_bounds__(256)
void icl_partial_kernel(const float* __restrict__ fwd,
                        const float* __restrict__ bwd,
                        float* __restrict__ partial) {
    const int tid = blockIdx.x * blockDim.x + threadIdx.x;
    const int b = tid >> 21;
    const int v = tid & (DHW - 1);
    const int z = v >> 14;
    const int y = (v >> 7) & 127;
    const int x = v & 127;

    const float* f = fwd + (size_t)b * 3 * DHW;
    const float fz = f[v];
    const float fy = f[v + DHW];
    const float fx = f[v + 2 * DHW];

    const float cz = (float)z + fz, cy = (float)y + fy, cx = (float)x + fx;
    const float z0f = floorf(cz), y0f = floorf(cy), x0f = floorf(cx);
    const float wz = cz - z0f, wy = cy - y0f, wx = cx - x0f;
    const int z0 = (int)z0f, y0 = (int)y0f, x0 = (int)x0f;

    const float* g = bwd + (size_t)b * 3 * DHW;
    float o0 = 0.f, o1 = 0.f, o2 = 0.f;
#pragma unroll
    for (int dz = 0; dz < 2; ++dz) {
        const int zi = z0 + dz;
        const bool vz = (zi >= 0) & (zi < DD);
        const int zc = min(max(zi, 0), DD - 1);
        const float az = dz ? wz : 1.f - wz;
#pragma unroll
        for (int dy = 0; dy < 2; ++dy) {
            const int yi = y0 + dy;
            const bool vy = (yi >= 0) & (yi < HH);
            const int yc = min(max(yi, 0), HH - 1);
            const float ay = dy ? wy : 1.f - wy;
#pragma unroll
            for (int dx = 0; dx < 2; ++dx) {
                const int xi = x0 + dx;
                const bool vx = (xi >= 0) & (xi < WW);
                const int xc = min(max(xi, 0), WW - 1);
                const float ax = dx ? wx : 1.f - wx;
                const float w = (vz & vy & vx) ? (az * ay * ax) : 0.f;
                const int idx = (zc * HH + yc) * WW + xc;
                o0 += w * g[idx];
                o1 += w * g[idx + DHW];
                o2 += w * g[idx + 2 * DHW];
            }
        }
    }
    const float c0 = fz + o0, c1 = fy + o1, c2 = fx + o2;
    float acc = c0 * c0 + c1 * c1 + c2 * c2;
#pragma unroll
    for (int off = 32; off > 0; off >>= 1)
        acc += __shfl_down(acc, off, 64);
    __shared__ float smem[4];
    if ((threadIdx.x & 63) == 0) smem[threadIdx.x >> 6] = acc;
    __syncthreads();
    if (threadIdx.x == 0)
        partial[blockIdx.x] = smem[0] + smem[1] + smem[2] + smem[3];
}

// ---------------------------------------------------------------------------
// Final deterministic reduction (double), divide by N, nan_to_num.
// ---------------------------------------------------------------------------
__global__ __launch_bounds__(256)
void icl_final_kernel(const float* __restrict__ partial, int n,
                      float* __restrict__ out) {
    double acc = 0.0;
    for (int i = threadIdx.x; i < n; i += 256)
        acc += (double)partial[i];
#pragma unroll
    for (int off = 32; off > 0; off >>= 1)
        acc += __shfl_down(acc, off, 64);
    __shared__ double smem[4];
    if ((threadIdx.x & 63) == 0) smem[threadIdx.x >> 6] = acc;
    __syncthreads();
    if (threadIdx.x == 0) {
        const double total = smem[0] + smem[1] + smem[2] + smem[3];
        float r = (float)(total / (double)NTOT);
        if (isnan(r)) r = 0.f;
        else if (isinf(r)) r = (r > 0.f) ? 1000.f : 0.f;
        out[0] = r;
    }
}

// ---------------------------------------------------------------------------
extern "C" void kernel_launch(void* const* d_in, const int* in_sizes, int n_in,
                              void* d_out, int out_size, void* d_ws, size_t ws_size,
                              hipStream_t stream) {
    const float* fwd = (const float*)d_in[0];
    const float* bwd = (const float*)d_in[1];
    float* out = (float*)d_out;
    float* partial = (float*)d_ws;

    if (ws_size >= WS_NEEDED) {
        unsigned* pk4 = (unsigned*)((char*)d_ws + WS_PARTIAL_BYTES);
        const int grid_pack = (1 << 20) / 256;           // 4096: full B*DHW
        icl_pack4_kernel<<<grid_pack, 256, 0, stream>>>(bwd, pk4);
        icl_lds_kernel<<<GRID_MAIN, 256, 0, stream>>>(fwd, pk4, partial);
        icl_final_kernel<<<1, 256, 0, stream>>>(partial, GRID_MAIN, out);
    } else {
        const int grid = (BATCH * DHW) / 256;            // 16384
        icl_partial_kernel<<<grid, 256, 0, stream>>>(fwd, bwd, partial);
        icl_final_kernel<<<1, 256, 0, stream>>>(partial, grid, out);
    }
}